// Round 8
// baseline (233.283 us; speedup 1.0000x reference)
//
#include <hip/hip_runtime.h>
#include <stdint.h>

// Problem: out[m][n] = sum_k x[m][k] * w[n][k] + bias[n]
//   M=256, N=16384, K=4096, w = dequant(2-bit, group=16 along k)
// Harness dtype universe {bf16,int32,float32}: fp16 weight_norm arrives as f32.
//
// History:
//  R3/R6/R7 (LDS-staged, 2 barriers/iter): all ~86-92 us. Per-CU rate constant
//    at ~1.65k cyc per 128x64x64 block-iter regardless of residency -> barrier
//    phases make pipe demands ADD. Fix = remove pipes + remove barriers.
//  R4/R5: VGPR state across barriers spills (WRITE_SIZE 190-287 MB). Avoided
//    here: there are NO barriers.
//  R8: wave-autonomous: no LDS, no syncthreads. A direct from chunked ws
//    (L1/L2), B dequanted into registers via permuted-K (one b128 q2 + one
//    nrm dword per u-frag per 64k-iter).
#define M_DIM 256
#define N_DIM 16384
#define K_DIM 4096
#define KSPLIT 2
#define KSLICE (K_DIM / KSPLIT)   // 2048

typedef __bf16 bf16x8 __attribute__((ext_vector_type(8)));
typedef float  f32x4  __attribute__((ext_vector_type(4)));

// fp32 -> bf16 bits, round-nearest-even (finite inputs)
__device__ __forceinline__ uint32_t f2bf(float f) {
  uint32_t u = __float_as_uint(f);
  return (u + 0x7fffu + ((u >> 16) & 1u)) >> 16;
}

// ---------------------------------------------------------------------------
// Kernel 1: x fp32 [256][4096] -> bf16 PERMUTED fragment-chunk order.
// 64k-chunk = 16 rows x 64 k = 2 KiB = 2 sub-chunks (ts) of 64 slots x 16B.
// Slot L of sub-chunk ts holds row (L&15), k = kch*64 + (L>>4)*16 + ts*8 .. +7.
// (qd=L>>4 spans GROUPS; ts spans group halves -- matches the B permuted-K
//  mapping so each B lane reads one contiguous group.)
// ws uint4 index = mb*8192 + kch*128 + ts*64 + L   (mb 0..15, kch 0..63)
// ---------------------------------------------------------------------------
__global__ __launch_bounds__(256) void cvt_x_kernel(const float* __restrict__ x,
                                                    uint4* __restrict__ ws) {
  int T = blockIdx.x * 256 + threadIdx.x;       // 0..131071
  int mb  = T >> 13;                            // 16 m-blocks
  int r   = T & 8191;
  int kch = r >> 7;                             // 64 k-chunks of 64
  int r2  = r & 127;
  int ts  = r2 >> 6;
  int L   = r2 & 63;
  int row = mb * 16 + (L & 15);
  int k   = kch * 64 + ((L >> 4) * 16) + ts * 8;
  const float* p = x + (size_t)row * K_DIM + k;
  float4 a = *(const float4*)p;
  float4 b = *(const float4*)(p + 4);
  uint4 o;
  o.x = f2bf(a.x) | (f2bf(a.y) << 16);
  o.y = f2bf(a.z) | (f2bf(a.w) << 16);
  o.z = f2bf(b.x) | (f2bf(b.y) << 16);
  o.w = f2bf(b.z) | (f2bf(b.w) << 16);
  ws[T] = o;   // T == mb*8192 + kch*128 + ts*64 + L
}

// ---------------------------------------------------------------------------
// Kernel 2: wave-autonomous 2-bit dequant + bf16 MFMA GEMM. NO LDS/barriers.
// Grid (N/128, M/128, KSPLIT), 256 thr = 4 waves (wm,wn in 2x2), wave tile
// 64x64 (4 s-frags x 4 u-frags), BK=64 per iter.
// Permuted-K within each 64k iter: lane quad qd <-> q2 group (kc/16 + qd);
// MFMA step ts <-> group half. A prepack (cvt) uses the same permutation.
// Dequant: v_perm 4-entry bf16 LUT, w in {-n, -n/3, +n/3, +n} (proven R6).
// k-halves combine via fp32 atomicAdd onto memset-zeroed out.
// ---------------------------------------------------------------------------
__global__ __launch_bounds__(256, 2) void gemm2bit_kernel(
    const uint4*    __restrict__ aws,  // A permuted fragment chunks (see cvt)
    const uint32_t* __restrict__ q2,   // [G][4] packed 2-bit (crumbs in bytes)
    const float*    __restrict__ nrm,  // [G] group norms (fp32)
    const float*    __restrict__ bias, // [N]
    float*          __restrict__ out)  // [256][16384] fp32, pre-zeroed
{
  const int tid  = threadIdx.x;
  const int l    = tid & 63;
  const int w    = tid >> 6;
  const int wm   = w >> 1;
  const int wn   = w & 1;
  const int lo4  = l & 15;
  const int qd   = l >> 4;

  const int n0    = blockIdx.x * 128 + wn * 64;   // wave n-base
  const int m0    = blockIdx.y * 128 + wm * 64;   // wave m-base
  const int kbase = blockIdx.z * KSLICE;

  f32x4 acc[4][4];
#pragma unroll
  for (int s = 0; s < 4; ++s)
#pragma unroll
    for (int u = 0; u < 4; ++u)
      acc[s][u] = (f32x4){0.f, 0.f, 0.f, 0.f};

  // A base (uint4 index): frag s lives at mb = by*8 + wm*4 + s
  const size_t abase = ((size_t)blockIdx.y * 8 + wm * 4) * 8192 + l;
  // B per-u group-index base (element: gidx = row*256 + kc/16 + qd)
  size_t gb[4];
#pragma unroll
  for (int u = 0; u < 4; ++u)
    gb[u] = (size_t)(n0 + u * 16 + lo4) * 256 + qd;

  for (int kc = kbase; kc < kbase + KSLICE; kc += 64) {
    const int kch = kc >> 6;   // 64k-chunk index
    const int kg  = kc >> 4;   // group column base

    // ---- A fragments: direct b128 loads from chunk-ordered ws (L1/L2) ----
    bf16x8 af[4][2];
#pragma unroll
    for (int s = 0; s < 4; ++s) {
#pragma unroll
      for (int ts = 0; ts < 2; ++ts)
        af[s][ts] = *(const bf16x8*)&aws[abase + (size_t)s * 8192 +
                                         (size_t)kch * 128 + ts * 64];
    }

    // ---- B fragments: one q2 b128 + one nrm dword per u, dequant in regs --
    bf16x8 bfr[4][2];
#pragma unroll
    for (int u = 0; u < 4; ++u) {
      const size_t gidx = gb[u] + kg;
      uint4 q  = *(const uint4*)(q2 + gidx * 4);
      float nv = nrm[gidx];
      uint32_t u3  = f2bf(nv);                          // bf(+n)
      uint32_t u1  = f2bf(nv * 0.33333334f);            // bf(+n/3)
      uint32_t T01 = (u3 | (u1 << 16)) ^ 0x80008000u;   // [-n, -n/3]
      uint32_t T23 = u1 | (u3 << 16);                   // [+n/3, +n]
      union { uint32_t r[8]; bf16x8 v[2]; } fr;
#pragma unroll
      for (int p = 0; p < 4; ++p) {                     // word p -> elems 4p..4p+3
        uint32_t qq  = (&q.x)[p];
        uint32_t v01 = (qq & 3u) | ((qq & 0x0Cu) << 14);
        uint32_t v23 = ((qq >> 4) & 3u) | ((qq & 0xC0u) << 10);
        fr.r[p * 2]     = __builtin_amdgcn_perm(T23, T01, v01 * 0x0202u + 0x01000100u);
        fr.r[p * 2 + 1] = __builtin_amdgcn_perm(T23, T01, v23 * 0x0202u + 0x01000100u);
      }
      bfr[u][0] = fr.v[0];   // group elems 0..7  (k = g*16 + 0..7,  ts=0)
      bfr[u][1] = fr.v[1];   // group elems 8..15 (k = g*16 + 8..15, ts=1)
    }

    // ---- 32 MFMAs ----
#pragma unroll
    for (int ts = 0; ts < 2; ++ts)
#pragma unroll
      for (int s = 0; s < 4; ++s)
#pragma unroll
        for (int u = 0; u < 4; ++u)
          acc[s][u] = __builtin_amdgcn_mfma_f32_16x16x32_bf16(
              af[s][ts], bfr[u][ts], acc[s][u], 0, 0, 0);
  }

  // ---- epilogue: C/D layout col=lane&15 (n), row=(lane>>4)*4+reg (m) ----
  float bv[4];
#pragma unroll
  for (int u = 0; u < 4; ++u)
    bv[u] = (blockIdx.z == 0) ? bias[n0 + u * 16 + lo4] : 0.0f;

#pragma unroll
  for (int s = 0; s < 4; ++s) {
    int mrow = m0 + s * 16 + qd * 4;
#pragma unroll
    for (int u = 0; u < 4; ++u) {
      int ncol = n0 + u * 16 + lo4;
      float* p = out + (size_t)mrow * N_DIM + ncol;
#pragma unroll
      for (int r = 0; r < 4; ++r)
        atomicAdd(p + (size_t)r * N_DIM, acc[s][u][r] + bv[u]);
    }
  }
}

// ---------------------------------------------------------------------------
extern "C" void kernel_launch(void* const* d_in, const int* in_sizes, int n_in,
                              void* d_out, int out_size, void* d_ws, size_t ws_size,
                              hipStream_t stream) {
  const float*    x    = (const float*)d_in[0];
  const uint32_t* q2   = (const uint32_t*)d_in[1];
  const float*    nm   = (const float*)d_in[2];
  const float*    bias = (const float*)d_in[3];
  float*          out  = (float*)d_out;
  uint4*          aws  = (uint4*)d_ws;   // 2 MiB: x as permuted bf16 chunks

  // zero output: k-split halves accumulate via atomicAdd
  hipMemsetAsync(d_out, 0, (size_t)out_size * sizeof(float), stream);

  cvt_x_kernel<<<512, 256, 0, stream>>>(x, aws);

  dim3 grid(N_DIM / 128, M_DIM / 128, KSPLIT);
  gemm2bit_kernel<<<grid, 256, 0, stream>>>(aws, q2, nm, bias, out);
}